// Round 1
// baseline (10.816 us; speedup 1.0000x reference)
//
#include <hip/hip_runtime.h>
#include <hip/hip_bf16.h>

// CenterLoss: loss = sum_b ||x[b] - centers[labels[b]]||^2 / BATCH
// x: [1024, 512] f32, labels: [1024] i32, centers: [100000, 512] f32
// out: scalar f32.

#define BATCH 1024
#define FEAT 512

// One block per row; 128 threads * float4 = 512 floats.
__global__ __launch_bounds__(128) void cl_row_kernel(
    const float* __restrict__ x,
    const int* __restrict__ labels,
    const float* __restrict__ centers,
    float* __restrict__ partial) {
    const int row = blockIdx.x;
    const int t = threadIdx.x;  // 0..127

    const int lab = labels[row];
    const float4* xr = reinterpret_cast<const float4*>(x + (size_t)row * FEAT);
    const float4* cr = reinterpret_cast<const float4*>(centers + (size_t)lab * FEAT);

    float4 a = xr[t];
    float4 b = cr[t];
    float dx = a.x - b.x;
    float dy = a.y - b.y;
    float dz = a.z - b.z;
    float dw = a.w - b.w;
    float s = dx * dx + dy * dy + dz * dz + dw * dw;

    // wave64 butterfly reduce
    #pragma unroll
    for (int off = 32; off > 0; off >>= 1)
        s += __shfl_down(s, off, 64);

    __shared__ float wsum[2];
    if ((t & 63) == 0) wsum[t >> 6] = s;
    __syncthreads();
    if (t == 0) partial[row] = wsum[0] + wsum[1];
}

// Single block reduces 1024 partials -> scalar
__global__ __launch_bounds__(256) void cl_final_kernel(
    const float* __restrict__ partial,
    float* __restrict__ out) {
    const int t = threadIdx.x;  // 0..255
    float4 v = reinterpret_cast<const float4*>(partial)[t];  // 1024 floats = 256 float4
    float s = v.x + v.y + v.z + v.w;

    #pragma unroll
    for (int off = 32; off > 0; off >>= 1)
        s += __shfl_down(s, off, 64);

    __shared__ float wsum[4];
    if ((t & 63) == 0) wsum[t >> 6] = s;
    __syncthreads();
    if (t == 0) out[0] = (wsum[0] + wsum[1] + wsum[2] + wsum[3]) * (1.0f / (float)BATCH);
}

extern "C" void kernel_launch(void* const* d_in, const int* in_sizes, int n_in,
                              void* d_out, int out_size, void* d_ws, size_t ws_size,
                              hipStream_t stream) {
    const float* x = (const float*)d_in[0];
    const int* labels = (const int*)d_in[1];
    const float* centers = (const float*)d_in[2];
    float* out = (float*)d_out;
    float* partial = (float*)d_ws;  // needs BATCH * 4 = 4 KiB

    cl_row_kernel<<<BATCH, 128, 0, stream>>>(x, labels, centers, partial);
    cl_final_kernel<<<1, 256, 0, stream>>>(partial, out);
}